// Round 11
// baseline (4524.741 us; speedup 1.0000x reference)
//
#include <hip/hip_runtime.h>
#include <hip/hip_bf16.h>

// PathRNN: h_{t+1} = tanh(x_t + W_hh h_t), u = h, pos = u @ W_out^T
// B=128, T=1024, H=512.
// ONE COHORT PER CU, 8 WGs x 256 thr = 4 waves x 1 wave/SIMD (512-reg budget).
// Wave w owns cols w*128..+127 (8 n-tiles). W_hh bf16: kt 0..11 in REGISTERS
// (384 regs/lane), kt 12..15 in LDS (128 KB). h single-buffered in LDS (16 KB,
// XOR swizzle) with raw BAR1/BAR2 per step (r10-proven). LDS-kt slots
// interleaved (3,7,11,15) so their W-reads hide under reg-kt MFMA bursts;
// every A-read feeds 8 independent MFMAs (155 cyc pipe) -> depth-1 prefetch
// covers LDS latency. MFMA pipe (~2500 cyc/step) is the designed floor.
// No atomics, no workspace, no cross-WG state: deterministic, replay-safe.

#define TT 1024
#define BB 128
#define HH 512

typedef short s16x8 __attribute__((ext_vector_type(8)));
typedef float f32x4 __attribute__((ext_vector_type(4)));
typedef unsigned int uint;
typedef unsigned short ushort_t;

#define MFMA_B16(a, b, c) __builtin_amdgcn_mfma_f32_16x16x32_bf16((a), (b), (c), 0, 0, 0)

static __device__ __forceinline__ ushort_t bf16_rne(float f) {
  uint u = __float_as_uint(f);
  u += 0x7fffu + ((u >> 16) & 1u);
  return (ushort_t)(u >> 16);
}

static __device__ __forceinline__ uint cvt_pk_bf16(float lo, float hi) {
  uint r;
  asm("v_cvt_pk_bf16_f32 %0, %1, %2" : "=v"(r) : "v"(lo), "v"(hi));
  return r;  // lo16 = bf16(lo), hi16 = bf16(hi), RNE
}

static __device__ __forceinline__ float tanh_fast(float z) {
  float e = __expf(2.0f * z);
  return 1.0f - 2.0f * __builtin_amdgcn_rcpf(e + 1.0f);
}

static __device__ __forceinline__ s16x8 packW(const float* wp) {
  float4 lo = *(const float4*)wp;
  float4 hi = *(const float4*)(wp + 4);
  s16x8 s;
  s[0] = (short)bf16_rne(lo.x); s[1] = (short)bf16_rne(lo.y);
  s[2] = (short)bf16_rne(lo.z); s[3] = (short)bf16_rne(lo.w);
  s[4] = (short)bf16_rne(hi.x); s[5] = (short)bf16_rne(hi.y);
  s[6] = (short)bf16_rne(hi.z); s[7] = (short)bf16_rne(hi.w);
  return s;
}

__global__ __launch_bounds__(256, 1) void rnn_kernel(
    const float* __restrict__ vel, const float* __restrict__ W_ih,
    const float* __restrict__ W_hh, const float* __restrict__ b_ih,
    const float* __restrict__ b_hh, float* __restrict__ u_out) {
  // LDS 144 KiB:
  //   @0      h [row 16][col 512] bf16, byte ^ ((row&7)<<4)   (16 KiB, single)
  //   @16384  W tail [kg 4][kti 4][n 512] x 16 B              (128 KiB)
  __shared__ uint4 lds_mem[9216];  // 147456 B
  char* hlds = (char*)lds_mem;

  const int tid = threadIdx.x;   // 0..255
  const int lane = tid & 63;
  const int w = tid >> 6;        // wave 0..3 -> 128-col strip
  const int c = blockIdx.x;      // cohort 0..7
  const int l15 = lane & 15;
  const int kg = lane >> 4;      // 0..3
  const int n0w = w * 128;

  // ---- one-time: W_hh kt 0..11 -> registers (8 nt x 12 kt = 384 regs) ----
  s16x8 wreg[8][12];
#pragma unroll
  for (int nt = 0; nt < 8; ++nt) {
    const float* wb = W_hh + (size_t)(n0w + nt * 16 + l15) * HH + kg * 8;
#pragma unroll
    for (int kt = 0; kt < 12; ++kt) wreg[nt][kt] = packW(wb + kt * 32);
  }

  // ---- one-time: W_hh kt 12..15 -> LDS [kg][kti][n]*16B ----
#pragma unroll
  for (int kti = 0; kti < 4; ++kti)
#pragma unroll
    for (int kq = 0; kq < 4; ++kq)
#pragma unroll
      for (int half = 0; half < 2; ++half) {
        int n = tid + half * 256;
        s16x8 s = packW(W_hh + (size_t)n * HH + (12 + kti) * 32 + kq * 8);
        *(s16x8*)(hlds + 16384 + (kq * 4 + kti) * 8192 + n * 16) = s;
      }

  // ---- input-projection coefficients (24 regs) ----
  float wihA[8], wihB[8], bsv[8];
#pragma unroll
  for (int nt = 0; nt < 8; ++nt) {
    int n = n0w + nt * 16 + l15;
    wihA[nt] = W_ih[n * 2 + 0];
    wihB[nt] = W_ih[n * 2 + 1];
    bsv[nt] = b_ih[n] + b_hh[n];
  }

  // ---- zero h (h_0 = 0): 16 KB / 256 threads ----
  {
    uint4 z = {0u, 0u, 0u, 0u};
    uint4* zp = (uint4*)(hlds + tid * 64);
    zp[0] = z; zp[1] = z; zp[2] = z; zp[3] = z;
  }
  __syncthreads();

  // ---- static addresses ----
  const uint aswz = ((uint)l15 & 7u) << 4;
  const uint abase = (uint)l15 * 1024u + (uint)kg * 16u;
  const char* pAe = hlds + (abase ^ aswz);          // even kt: + (kt>>1)*128
  const char* pAo = hlds + ((abase + 64u) ^ aswz);  // odd  kt: + (kt>>1)*128
  const char* pW = hlds + 16384 + kg * 32768 + (n0w + l15) * 16;

  const bool odd = (l15 & 1) != 0;
  const uint rowb0 = (uint)(kg * 4) + (odd ? 2u : 0u);
  const uint rowb1 = rowb0 + 1u;
  const uint wr0 = rowb0 * 1024u + (uint)(n0w + (l15 & ~1)) * 2u;
  const uint wr1 = rowb1 * 1024u + (uint)(n0w + (l15 & ~1)) * 2u;
  const uint swz0 = (rowb0 & 7u) << 4;
  const uint swz1 = (rowb1 & 7u) << 4;

  uint uoff[4];
#pragma unroll
  for (int r = 0; r < 4; ++r)
    uoff[r] = (uint)(c * 16 + kg * 4 + r) * (uint)(TT * HH) + (uint)(n0w + l15);
  const float* velb = vel + (size_t)(c * 16 + kg * 4) * (TT * 2);

#define LDA(kt) ((kt & 1) ? *(const s16x8*)(pAo + ((kt) >> 1) * 128) \
                          : *(const s16x8*)(pAe + ((kt) >> 1) * 128))

  const f32x4 z4 = {0.f, 0.f, 0.f, 0.f};
  // K-slot order: LDS-kts (12..15) interleaved so their reads hide under
  // neighboring reg-kt MFMA bursts.
  const int ord[16] = {0, 1, 2, 12, 3, 4, 5, 13, 6, 7, 8, 14, 9, 10, 11, 15};

  for (int t = 0; t < TT; ++t) {
    // vel loads for this step (4 rows)
    const float* vb = velb + t * 2;
    float2 v0 = *(const float2*)(vb);
    float2 v1 = *(const float2*)(vb + 2048);
    float2 v2 = *(const float2*)(vb + 4096);
    float2 v3 = *(const float2*)(vb + 6144);

    f32x4 acc[8] = {z4, z4, z4, z4, z4, z4, z4, z4};

    // ---- K loop: 12 reg-kt + 4 LDS-kt (interleaved), A prefetch depth 1 ----
    s16x8 aF = LDA(ord[0]);
#pragma unroll
    for (int i = 0; i < 16; ++i) {
      const int kt = ord[i];
      s16x8 aN;
      if (i < 15) { const int kn = ord[i + 1]; aN = LDA(kn); }
      if (kt < 12) {
#pragma unroll
        for (int nt = 0; nt < 8; ++nt) acc[nt] = MFMA_B16(aF, wreg[nt][kt], acc[nt]);
      } else {
        const char* wp = pW + (kt - 12) * 8192;
        {
          s16x8 b0 = *(const s16x8*)(wp);
          s16x8 b1 = *(const s16x8*)(wp + 256);
          s16x8 b2 = *(const s16x8*)(wp + 512);
          s16x8 b3 = *(const s16x8*)(wp + 768);
          acc[0] = MFMA_B16(aF, b0, acc[0]);
          acc[1] = MFMA_B16(aF, b1, acc[1]);
          acc[2] = MFMA_B16(aF, b2, acc[2]);
          acc[3] = MFMA_B16(aF, b3, acc[3]);
        }
        {
          s16x8 b4 = *(const s16x8*)(wp + 1024);
          s16x8 b5 = *(const s16x8*)(wp + 1280);
          s16x8 b6 = *(const s16x8*)(wp + 1536);
          s16x8 b7 = *(const s16x8*)(wp + 1792);
          acc[4] = MFMA_B16(aF, b4, acc[4]);
          acc[5] = MFMA_B16(aF, b5, acc[5]);
          acc[6] = MFMA_B16(aF, b6, acc[6]);
          acc[7] = MFMA_B16(aF, b7, acc[7]);
        }
      }
      aF = aN;
    }

    // ---- epilogue: x + tanh, u-store (fire-and-forget), pack col-pairs ----
    float* ub = u_out + (size_t)t * HH;
    uint pr0v[8], pr1v[8];
#pragma unroll
    for (int nt = 0; nt < 8; ++nt) {
      float uvr[4];
      float2 vv[4] = {v0, v1, v2, v3};
#pragma unroll
      for (int r = 0; r < 4; ++r) {
        float x = fmaf(vv[r].x, wihA[nt], fmaf(vv[r].y, wihB[nt], bsv[nt]));
        uvr[r] = tanh_fast(x + acc[nt][r]);
        __builtin_nontemporal_store(uvr[r], ub + uoff[r] + nt * 16);
      }
      uint a01 = cvt_pk_bf16(uvr[0], uvr[1]);
      uint a23 = cvt_pk_bf16(uvr[2], uvr[3]);
      uint b01 = __shfl_xor(a01, 1);
      uint b23 = __shfl_xor(a23, 1);
      uint eP = odd ? b23 : a01;  // even col, rows (rowb0, rowb0+1)
      uint oP = odd ? a23 : b01;  // odd col
      pr0v[nt] = (eP & 0xFFFFu) | (oP << 16);
      pr1v[nt] = (eP >> 16) | (oP & 0xFFFF0000u);
    }

    // BAR1: all waves done READING h(t) (A-reads consumed by MFMAs; acc
    // consumed by epilogue above). Safe to overwrite h.
    asm volatile("s_barrier" ::: "memory");

#pragma unroll
    for (int nt = 0; nt < 8; ++nt) {
      *(uint*)(hlds + ((wr0 + (uint)(nt * 32)) ^ swz0)) = pr0v[nt];
      *(uint*)(hlds + ((wr1 + (uint)(nt * 32)) ^ swz1)) = pr1v[nt];
    }
    asm volatile("s_waitcnt lgkmcnt(0)" ::: "memory");
    __builtin_amdgcn_sched_barrier(0);
    // BAR2: h(t+1) fully visible. vmcnt NOT drained (u-stores in flight).
    asm volatile("s_barrier" ::: "memory");
  }
}

// pos[b,t,:] = u[b,t,:] @ W_out^T + b_out ; one wave per (b,t) row, BW-bound.
__global__ __launch_bounds__(256) void pos_kernel(const float* __restrict__ u,
                                                  const float* __restrict__ W_out,
                                                  const float* __restrict__ b_out,
                                                  float* __restrict__ pos) {
  int row = blockIdx.x * 4 + (threadIdx.x >> 6);
  int lane = threadIdx.x & 63;
  const float* ur = u + (size_t)row * HH + lane * 8;
  float4 u0 = *(const float4*)ur;
  float4 u1 = *(const float4*)(ur + 4);
  float4 w00 = *(const float4*)(W_out + lane * 8);
  float4 w01 = *(const float4*)(W_out + lane * 8 + 4);
  float4 w10 = *(const float4*)(W_out + HH + lane * 8);
  float4 w11 = *(const float4*)(W_out + HH + lane * 8 + 4);
  float p0 = u0.x * w00.x + u0.y * w00.y + u0.z * w00.z + u0.w * w00.w +
             u1.x * w01.x + u1.y * w01.y + u1.z * w01.z + u1.w * w01.w;
  float p1 = u0.x * w10.x + u0.y * w10.y + u0.z * w10.z + u0.w * w10.w +
             u1.x * w11.x + u1.y * w11.y + u1.z * w11.z + u1.w * w11.w;
#pragma unroll
  for (int off = 32; off; off >>= 1) {
    p0 += __shfl_xor(p0, off);
    p1 += __shfl_xor(p1, off);
  }
  if (lane == 0) {
    pos[(size_t)row * 2 + 0] = p0 + b_out[0];
    pos[(size_t)row * 2 + 1] = p1 + b_out[1];
  }
}

extern "C" void kernel_launch(void* const* d_in, const int* in_sizes, int n_in,
                              void* d_out, int out_size, void* d_ws, size_t ws_size,
                              hipStream_t stream) {
  const float* vel   = (const float*)d_in[0];
  const float* W_ih  = (const float*)d_in[1];
  const float* W_hh  = (const float*)d_in[2];
  const float* b_ih  = (const float*)d_in[3];
  const float* b_hh  = (const float*)d_in[4];
  const float* W_out = (const float*)d_in[5];
  const float* b_out = (const float*)d_in[6];

  float* pos = (float*)d_out;              // [B,T,2]
  float* u   = pos + (size_t)BB * TT * 2;  // [B,T,H]

  // No workspace, no inter-WG state: deterministic, replay-safe by design.
  rnn_kernel<<<8, 256, 0, stream>>>(vel, W_ih, W_hh, b_ih, b_hh, u);
  pos_kernel<<<(BB * TT) / 4, 256, 0, stream>>>(u, W_out, b_out, pos);
}